// Round 3
// baseline (39.685 us; speedup 1.0000x reference)
//
#include <hip/hip_runtime.h>
#include <math.h>

#define NN 512
#define D  256   // EMB_DIM == HID

// Kernel 1: block b<128 -> x-rows, b>=128 -> y-rows. 512 threads: t&255 = k,
// t>>8 selects a 2-row subset. x/y row loads are wave-uniform (s_load),
// W loads coalesced. x-side writes the TRANSPOSE hxbT[k][j] (registers already
// hold it); y-side writes hy row-major (consumed as wave-uniform rows later).
__global__ __launch_bounds__(512) void gemm_rows(
    const float* __restrict__ x, const float* __restrict__ y,
    const float* __restrict__ W1, const float* __restrict__ b1,
    float* __restrict__ hxbT, float* __restrict__ hy,
    unsigned int* __restrict__ counter)
{
    if (blockIdx.x == 0 && threadIdx.x == 0) *counter = 0u;  // reset for kernel 2

    int b = blockIdx.x;                 // 0..255
    bool isx = (b < 128);
    int r0 = (b & 127) * 4 + (threadIdx.x >> 8) * 2;   // 2 rows per half-block
    int t = threadIdx.x & 255;          // k (output column)
    const float* src = isx ? x : y;
    const float* Wb = W1 + (isx ? 0 : D * D);

    float bias = isx ? b1[t] : 0.0f;
    float a0 = bias, a1 = bias;

    const float4* s0 = (const float4*)(src + (r0 + 0) * D);
    const float4* s1 = (const float4*)(src + (r0 + 1) * D);

#pragma unroll 4
    for (int m4 = 0; m4 < D / 4; ++m4) {
        float4 v0 = s0[m4], v1 = s1[m4];            // wave-uniform -> scalar
        const float* Wc = Wb + (m4 * 4) * D + t;
        float w0 = Wc[0], w1 = Wc[D], w2 = Wc[2 * D], w3 = Wc[3 * D]; // coalesced
        a0 = fmaf(v0.x, w0, a0); a0 = fmaf(v0.y, w1, a0);
        a0 = fmaf(v0.z, w2, a0); a0 = fmaf(v0.w, w3, a0);
        a1 = fmaf(v1.x, w0, a1); a1 = fmaf(v1.y, w1, a1);
        a1 = fmaf(v1.z, w2, a1); a1 = fmaf(v1.w, w3, a1);
    }

    if (isx) {
        // transpose for free: thread holds (k=t, j=r0..r0+1)
        float2 v = make_float2(a0, a1);
        *(float2*)(hxbT + t * NN + r0) = v;     // r0 even -> 8B aligned
    } else {
        hy[(r0 + 0) * D + t] = a0;              // coalesced
        hy[(r0 + 1) * D + t] = a1;
    }
}

// Kernel 2: block b owns i = {2b, 2b+1}. 512 threads: jg = t&127 owns
// j = 4jg..4jg+3 (coalesced float4 from hxbT), ks = t>>7 owns a 64-wide
// k-slice (wave-uniform -> hy/W2 scalar loads). k-partials combined in LDS.
// exp(softplus(z)) == 1 + exp(z) -> lse_i = log(512 + sum_j exp(z_ij)).
__global__ __launch_bounds__(512) void pair_kernel(
    const float* __restrict__ hxbT, const float* __restrict__ hy,
    const float* __restrict__ W2, const float* __restrict__ b2p,
    float* __restrict__ partials, unsigned int* __restrict__ counter,
    float* __restrict__ out)
{
    int b = blockIdx.x;         // 0..255
    int i0 = b * 2;
    int t = threadIdx.x;        // 0..511
    int jg = t & 127;           // j-group base: 4*jg
    int ks = t >> 7;            // k-slice 0..3 (uniform within each wave)

    const float* hy0 = hy + (i0 + 0) * D;   // wave-uniform rows
    const float* hy1 = hy + (i0 + 1) * D;

    float p00 = 0.f, p01 = 0.f, p02 = 0.f, p03 = 0.f;
    float p10 = 0.f, p11 = 0.f, p12 = 0.f, p13 = 0.f;

    const float4* hT = (const float4*)hxbT;  // hxbT[k][j] as float4 rows of 128
    int kbase = ks * 64;
#pragma unroll 4
    for (int kk = 0; kk < 64; ++kk) {
        int k = kbase + kk;
        float4 hv = hT[k * (NN / 4) + jg];   // coalesced: 16B/lane contiguous
        float a = hy0[k], c = hy1[k], w = W2[k];   // wave-uniform -> s_load
        p00 = fmaf(fmaxf(hv.x + a, 0.f), w, p00);
        p01 = fmaf(fmaxf(hv.y + a, 0.f), w, p01);
        p02 = fmaf(fmaxf(hv.z + a, 0.f), w, p02);
        p03 = fmaf(fmaxf(hv.w + a, 0.f), w, p03);
        p10 = fmaf(fmaxf(hv.x + c, 0.f), w, p10);
        p11 = fmaf(fmaxf(hv.y + c, 0.f), w, p11);
        p12 = fmaf(fmaxf(hv.z + c, 0.f), w, p12);
        p13 = fmaf(fmaxf(hv.w + c, 0.f), w, p13);
    }

    __shared__ float zS[4][2][NN];   // 16 KB, [ks][i][j]
    *(float4*)&zS[ks][0][4 * jg] = make_float4(p00, p01, p02, p03);
    *(float4*)&zS[ks][1][4 * jg] = make_float4(p10, p11, p12, p13);
    __syncthreads();

    // thread t == j
    float b2 = b2p[0];
    float z0 = zS[0][0][t] + zS[1][0][t] + zS[2][0][t] + zS[3][0][t] + b2;
    float z1 = zS[0][1][t] + zS[1][1][t] + zS[2][1][t] + zS[3][1][t] + b2;
    float e0 = expf(z0), e1 = expf(z1);   // exp(softplus(z)) = 1 + e^z

    __shared__ float ws0[8], ws1[8], diagS[2];
    __shared__ int islastS;
    int lane = t & 63, wid = t >> 6;

    if (t == i0)     diagS[0] = fmaxf(z0, 0.f) + log1pf(expf(-fabsf(z0)));
    if (t == i0 + 1) diagS[1] = fmaxf(z1, 0.f) + log1pf(expf(-fabsf(z1)));

    float s0 = e0, s1 = e1;
#pragma unroll
    for (int off = 32; off >= 1; off >>= 1) {
        s0 += __shfl_xor(s0, off);
        s1 += __shfl_xor(s1, off);
    }
    if (lane == 0) { ws0[wid] = s0; ws1[wid] = s1; }
    __syncthreads();

    if (t == 0) {
        float tot0 = 512.0f, tot1 = 512.0f;   // the "+1" from each of 512 j's
#pragma unroll
        for (int w = 0; w < 8; ++w) { tot0 += ws0[w]; tot1 += ws1[w]; }
        float lse0 = logf(tot0), lse1 = logf(tot1);
        float part = (lse0 - diagS[0] + lse1 - diagS[1]) * (1.0f / 512.0f);
        if (b == 0) part -= logf(512.0f);
        __hip_atomic_store(&partials[b], part, __ATOMIC_RELEASE, __HIP_MEMORY_SCOPE_AGENT);
        unsigned prev = __hip_atomic_fetch_add(counter, 1u, __ATOMIC_ACQ_REL, __HIP_MEMORY_SCOPE_AGENT);
        islastS = (prev == 255u) ? 1 : 0;
    }
    __syncthreads();

    // Last block reduces all 256 partials in a FIXED order -> deterministic.
    if (islastS && t < 64) {
        float s = 0.0f;
#pragma unroll
        for (int q = 0; q < 4; ++q)
            s += __hip_atomic_load(&partials[t + 64 * q], __ATOMIC_ACQUIRE, __HIP_MEMORY_SCOPE_AGENT);
#pragma unroll
        for (int off = 32; off >= 1; off >>= 1) s += __shfl_xor(s, off);
        if (t == 0) out[0] = s;   // = mean(lse) - log N - mean(T0)
    }
}

extern "C" void kernel_launch(void* const* d_in, const int* in_sizes, int n_in,
                              void* d_out, int out_size, void* d_ws, size_t ws_size,
                              hipStream_t stream)
{
    const float* x  = (const float*)d_in[0];
    const float* y  = (const float*)d_in[1];
    const float* W1 = (const float*)d_in[2];
    const float* b1 = (const float*)d_in[3];
    const float* W2 = (const float*)d_in[4];
    const float* b2 = (const float*)d_in[5];
    float* out = (float*)d_out;

    float* ws   = (float*)d_ws;
    float* hxbT = ws;                        // 256 k x 512 j
    float* hy   = ws + NN * D;               // 512 x 256
    float* partials = ws + 2 * NN * D;       // 256
    unsigned int* counter = (unsigned int*)(ws + 2 * NN * D + 256);

    gemm_rows<<<256, 512, 0, stream>>>(x, y, W1, b1, hxbT, hy, counter);
    pair_kernel<<<256, 512, 0, stream>>>(hxbT, hy, W2, b2, partials, counter, out);
}